// Round 3
// baseline (2190.089 us; speedup 1.0000x reference)
//
#include <hip/hip_runtime.h>
#include <hip/hip_bf16.h>

// Problem constants (fixed by setup_inputs)
#define BATCH 512
#define HDIM  1024
#define G4    4096   // 4*H
#define DSTEP 64
#define NOUT  512

typedef __bf16 bf16;
typedef __bf16 bf16x8 __attribute__((ext_vector_type(8)));
typedef float  f32x4  __attribute__((ext_vector_type(4)));

#define MFMA16(a, b, c) __builtin_amdgcn_mfma_f32_16x16x32_bf16((a), (b), (c), 0, 0, 0)

#define GLOAD_LDS16(g, l)                                                           \
    __builtin_amdgcn_global_load_lds((const __attribute__((address_space(1))) void*)(g), \
                                     (__attribute__((address_space(3))) void*)(l), 16, 0, 0)

__device__ __forceinline__ float sigmoid_f(float x) { return 1.0f / (1.0f + __expf(-x)); }
__device__ __forceinline__ float tanh_f(float x)    { return 1.0f - 2.0f / (__expf(2.0f * x) + 1.0f); }

// segment swizzle for [row][32] bf16 LDS tiles (4 segments of 16B per 64B row)
__device__ __forceinline__ int swz4(int row) { return (row ^ (row >> 2)) & 3; }

// ---------------- prep: fp32 -> bf16 conversions + state init ----------------
__global__ void prep_kernel(const float* __restrict__ x, const float* __restrict__ h0,
                            const float* __restrict__ c0, const float* __restrict__ W_ih,
                            const float* __restrict__ W_hh, const float* __restrict__ W_out,
                            bf16* __restrict__ x_b, bf16* __restrict__ Wih_b,
                            bf16* __restrict__ Whh_b, bf16* __restrict__ Wout_b,
                            bf16* __restrict__ h_slot0, float* __restrict__ c) {
    int tid = blockIdx.x * blockDim.x + threadIdx.x;
    int stride = gridDim.x * blockDim.x;
    for (int i = tid; i < G4 * HDIM; i += stride) {
        Whh_b[i] = (bf16)W_hh[i];
        Wih_b[i] = (bf16)W_ih[i];
    }
    for (int i = tid; i < BATCH * HDIM; i += stride) {
        x_b[i]    = (bf16)x[i];
        Wout_b[i] = (bf16)W_out[i];
        h_slot0[i] = (bf16)h0[i];
        c[i] = c0[i];
    }
}

// ---------------- tiled C = A @ B^T + bias (bf16 in, f32 out) ----------------
// 128x128 tile, BK=32, double-buffered LDS via global_load_lds(16B), 4 waves (64x64 each).
template <int M, int N, int K>
__global__ __launch_bounds__(256) void gemm_bt_tiled(const bf16* __restrict__ A,
                                                     const bf16* __restrict__ Bw,
                                                     const float* __restrict__ bias,
                                                     float* __restrict__ C) {
    constexpr int MT = M / 128;
    constexpr int NT = N / 128;
    constexpr int TOT = MT * NT;
    __shared__ bf16 sA[2][128 * 32];
    __shared__ bf16 sB[2][128 * 32];

    int bid = blockIdx.x;
    int g = (bid & 7) * (TOT / 8) + (bid >> 3);  // XCD-chunked
    int nt = g % NT, mt = g / NT;
    int mrow0 = mt * 128, ncol0 = nt * 128;

    int tid = threadIdx.x;
    int l = tid & 63;
    int w = tid >> 6;           // wave 0..3
    int wr = w >> 1, wc = w & 1;  // wave tile (64x64) within 128x128
    int lr = l & 15, q = l >> 4;

    const bf16* Abase = A + (size_t)mrow0 * K;
    const bf16* Bbase = Bw + (size_t)ncol0 * K;

    // stage one [128][32] tile (A or B) for K-step s into buf
    auto stage = [&](const bf16* base, bf16* dst, int k0) {
#pragma unroll
        for (int j = 0; j < 2; ++j) {
            int pbase = w * 64 + 256 * j;      // wave-uniform slot base
            int p = pbase + l;                 // this lane's 16B slot
            int row = p >> 2, seg = p & 3;
            int sseg = seg ^ swz4(row);        // pre-swizzled source segment
            const bf16* gp = base + (size_t)row * K + k0 + sseg * 8;
            GLOAD_LDS16(gp, dst + pbase * 8);  // wave-uniform LDS base + lane*16
        }
    };

    stage(Abase, sA[0], 0);
    stage(Bbase, sB[0], 0);
    __syncthreads();

    f32x4 acc[4][4] = {};
    constexpr int NS = K / 32;
    for (int s = 0; s < NS; ++s) {
        int cur = s & 1;
        if (s + 1 < NS) {
            stage(Abase, sA[cur ^ 1], (s + 1) * 32);
            stage(Bbase, sB[cur ^ 1], (s + 1) * 32);
        }
        bf16x8 af[4], bf[4];
#pragma unroll
        for (int fm = 0; fm < 4; ++fm) {
            int row = wr * 64 + fm * 16 + lr;
            af[fm] = *(const bf16x8*)&sA[cur][row * 32 + 8 * (q ^ swz4(row))];
        }
#pragma unroll
        for (int fn = 0; fn < 4; ++fn) {
            int row = wc * 64 + fn * 16 + lr;
            bf[fn] = *(const bf16x8*)&sB[cur][row * 32 + 8 * (q ^ swz4(row))];
        }
#pragma unroll
        for (int fm = 0; fm < 4; ++fm)
#pragma unroll
            for (int fn = 0; fn < 4; ++fn)
                acc[fm][fn] = MFMA16(af[fm], bf[fn], acc[fm][fn]);
        __syncthreads();
    }

    // epilogue: C/D layout col=lane&15, row=(lane>>4)*4+r
#pragma unroll
    for (int fm = 0; fm < 4; ++fm)
#pragma unroll
        for (int fn = 0; fn < 4; ++fn) {
            int col = ncol0 + wc * 64 + fn * 16 + lr;
            float bs = bias[col];
#pragma unroll
            for (int r = 0; r < 4; ++r) {
                int row = mrow0 + wr * 64 + fm * 16 + q * 4 + r;
                C[(size_t)row * N + col] = acc[fm][fn][r] + bs;
            }
        }
}

// ---------------- fused LSTM step v2: gate-split waves ----------------
// 512 blocks x 256 threads. Block tile: 32 batch x 32 hcols, all 4 gates.
// Wave gt computes gate gt's 32x32 tile over full K=1024 (no K-split, no reduce).
__global__ __launch_bounds__(256) void lstm_step2(const bf16* __restrict__ h_prev,  // [512][1024]
                                                  const bf16* __restrict__ Whh,     // [4096][1024]
                                                  const float* __restrict__ xW,     // [512][4096]
                                                  const float* __restrict__ b_hh,   // [4096]
                                                  float* __restrict__ c,            // [512][1024]
                                                  bf16* __restrict__ h_out) {       // [512][1024]
    __shared__ float gbuf[4][32][33];  // +1 pad

    int bid = blockIdx.x;              // 512 blocks
    int xcd = bid & 7;
    int idx = bid >> 3;                // 0..63
    int bt = idx >> 2;                 // 0..15
    int ht = xcd * 4 + (idx & 3);      // 0..31 (XCD-chunked h panels)

    int b0 = bt * 32;
    int hc0 = ht * 32;

    int tid = threadIdx.x;
    int l = tid & 63;
    int gt = tid >> 6;                 // wave = gate
    int lr = l & 15, lk = (l >> 4) * 8;

    const bf16* Ap = h_prev + (size_t)(b0 + lr) * HDIM + lk;
    const bf16* Bp = Whh + (size_t)(gt * HDIM + hc0 + lr) * HDIM + lk;

    f32x4 acc[2][2] = {};
#pragma unroll
    for (int ki = 0; ki < 32; ++ki) {
        int k0 = ki * 32;
        bf16x8 a0 = *(const bf16x8*)(Ap + k0);
        bf16x8 a1 = *(const bf16x8*)(Ap + (size_t)16 * HDIM + k0);
        bf16x8 bb0 = *(const bf16x8*)(Bp + k0);
        bf16x8 bb1 = *(const bf16x8*)(Bp + (size_t)16 * HDIM + k0);
        acc[0][0] = MFMA16(a0, bb0, acc[0][0]);
        acc[0][1] = MFMA16(a0, bb1, acc[0][1]);
        acc[1][0] = MFMA16(a1, bb0, acc[1][0]);
        acc[1][1] = MFMA16(a1, bb1, acc[1][1]);
    }

    // dump this wave's gate tile to LDS
#pragma unroll
    for (int fm = 0; fm < 2; ++fm)
#pragma unroll
        for (int fn = 0; fn < 2; ++fn)
#pragma unroll
            for (int r = 0; r < 4; ++r)
                gbuf[gt][fm * 16 + (l >> 4) * 4 + r][fn * 16 + lr] = acc[fm][fn][r];
    __syncthreads();

    // elementwise LSTM update: 1024 elems, 4 per thread
#pragma unroll
    for (int e = 0; e < 4; ++e) {
        int elem = e * 256 + tid;
        int row = elem >> 5, col = elem & 31;
        int grow = b0 + row;
        int gcol = hc0 + col;
        const float* xWr = xW + (size_t)grow * G4;
        float gi = gbuf[0][row][col] + xWr[gcol]             + b_hh[gcol];
        float gf = gbuf[1][row][col] + xWr[HDIM + gcol]      + b_hh[HDIM + gcol];
        float gg = gbuf[2][row][col] + xWr[2 * HDIM + gcol]  + b_hh[2 * HDIM + gcol];
        float go = gbuf[3][row][col] + xWr[3 * HDIM + gcol]  + b_hh[3 * HDIM + gcol];
        size_t cix = (size_t)grow * HDIM + gcol;
        float cc = c[cix];
        float cn = sigmoid_f(gf) * cc + sigmoid_f(gi) * tanh_f(gg);
        float hn = sigmoid_f(go) * tanh_f(cn);
        c[cix] = cn;
        h_out[cix] = (bf16)hn;
    }
}

// ---------------- launch ----------------
extern "C" void kernel_launch(void* const* d_in, const int* in_sizes, int n_in,
                              void* d_out, int out_size, void* d_ws, size_t ws_size,
                              hipStream_t stream) {
    const float* x    = (const float*)d_in[0];
    const float* h0   = (const float*)d_in[1];
    const float* c0   = (const float*)d_in[2];
    const float* W_ih = (const float*)d_in[3];
    const float* W_hh = (const float*)d_in[4];
    const float* b_ih = (const float*)d_in[5];
    const float* b_hh = (const float*)d_in[6];
    const float* W_out= (const float*)d_in[7];
    const float* b_out= (const float*)d_in[8];

    char* ws = (char*)d_ws;
    bf16*  Whh_b  = (bf16*)(ws + 0);                     // 8 MB
    bf16*  Wih_b  = (bf16*)(ws + (size_t)(8 << 20));     // 8 MB
    bf16*  x_b    = (bf16*)(ws + (size_t)(16 << 20));    // 1 MB
    bf16*  Wout_b = (bf16*)(ws + (size_t)(17 << 20));    // 1 MB
    float* xWbuf  = (float*)(ws + (size_t)(18 << 20));   // 8 MB
    float* cbuf   = (float*)(ws + (size_t)(26 << 20));   // 2 MB
    bf16*  h_all  = (bf16*)(ws + (size_t)(28 << 20));    // 65 MB (65 slots of 512x1024)

    const size_t HB = (size_t)BATCH * HDIM;

    prep_kernel<<<2048, 256, 0, stream>>>(x, h0, c0, W_ih, W_hh, W_out,
                                          x_b, Wih_b, Whh_b, Wout_b, h_all, cbuf);

    // xW = x @ W_ih^T + b_ih : M=512, N=4096 -> 128 blocks
    gemm_bt_tiled<BATCH, G4, HDIM><<<128, 256, 0, stream>>>(x_b, Wih_b, b_ih, xWbuf);

    for (int t = 0; t < DSTEP; ++t) {
        lstm_step2<<<512, 256, 0, stream>>>(h_all + (size_t)t * HB, Whh_b, xWbuf, b_hh,
                                            cbuf, h_all + (size_t)(t + 1) * HB);
    }

    // outs = h_all[1..64] @ W_out^T + b_out : M=32768, N=512 -> 1024 blocks
    gemm_bt_tiled<DSTEP * BATCH, NOUT, HDIM><<<1024, 256, 0, stream>>>(h_all + HB, Wout_b, b_out,
                                                                       (float*)d_out);
}